// Round 1
// baseline (845.688 us; speedup 1.0000x reference)
//
#include <hip/hip_runtime.h>
#include <hip/hip_bf16.h>
#include <stdint.h>

typedef unsigned short u16;
typedef __attribute__((ext_vector_type(4))) float f32x4;
typedef __attribute__((ext_vector_type(8))) short s16x8;
typedef __attribute__((ext_vector_type(8))) __bf16 b16x8;

constexpr int NB = 2, SEQ = 2048, HD = 2048, NHEADS = 16, DHEAD = 128;
constexpr int MROWS = NB * SEQ;  // 4096

__device__ __forceinline__ u16 f2b(float f) {
  __hip_bfloat16 h = __float2bfloat16(f);
  return __builtin_bit_cast(u16, h);
}
__device__ __forceinline__ float b2f(u16 u) {
  return __bfloat162float(__builtin_bit_cast(__hip_bfloat16, u));
}
__device__ __forceinline__ f32x4 mfma_bf16(s16x8 a, s16x8 b, f32x4 c) {
  return __builtin_amdgcn_mfma_f32_16x16x32_bf16(
      __builtin_bit_cast(b16x8, a), __builtin_bit_cast(b16x8, b), c, 0, 0, 0);
}
__device__ __forceinline__ void gload_lds16(const void* g, void* l) {
  __builtin_amdgcn_global_load_lds(
      (__attribute__((address_space(1))) void*)(const_cast<void*>(g)),
      (__attribute__((address_space(3))) void*)(l), 16, 0, 0);
}

// ---------------- f32 -> bf16 convert (8 elems / thread) ----------------
__global__ void cvt_bf16(const float* __restrict__ in, u16* __restrict__ out, int n8) {
  int i = blockIdx.x * blockDim.x + threadIdx.x;
  if (i >= n8) return;
  const float4* p = (const float4*)(in + (size_t)i * 8);
  float4 a = p[0], b = p[1];
  ushort4* q = (ushort4*)(out + (size_t)i * 8);
  q[0] = make_ushort4(f2b(a.x), f2b(a.y), f2b(a.z), f2b(a.w));
  q[1] = make_ushort4(f2b(b.x), f2b(b.y), f2b(b.z), f2b(b.w));
}

// ---------------- NT GEMM: C[M,N] = A[M,K] * B[N,K]^T (+bias) ----------------
// 128x128 tile, BK=32, 4 waves each 64x64. m97-style global_load_lds staging.
template <bool FBIAS>
__global__ __launch_bounds__(256, 2) void gemm_nt(
    const u16* __restrict__ A, const u16* __restrict__ B, void* __restrict__ Cv,
    const float* __restrict__ bias, int Kd, int Nd) {
  __shared__ __align__(16) u16 Alds[128 * 32];
  __shared__ __align__(16) u16 Blds[128 * 32];
  const int t = threadIdx.x;
  const int lane = t & 63, w = t >> 6;
  const int lr = lane & 15, lg = lane >> 4;
  const int wr = (w >> 1) * 64, wc = (w & 1) * 64;
  const int trow = blockIdx.y * 128, tcol = blockIdx.x * 128;

  f32x4 acc[4][4] = {};

  const int c0 = t, c1 = t + 256;  // 16B chunk ids (512 per operand tile)
  const u16* gA0 = A + (size_t)(trow + (c0 >> 2)) * Kd + (c0 & 3) * 8;
  const u16* gA1 = A + (size_t)(trow + (c1 >> 2)) * Kd + (c1 & 3) * 8;
  const u16* gB0 = B + (size_t)(tcol + (c0 >> 2)) * Kd + (c0 & 3) * 8;
  const u16* gB1 = B + (size_t)(tcol + (c1 >> 2)) * Kd + (c1 & 3) * 8;
  u16* lA0 = Alds + c0 * 8; u16* lA1 = Alds + c1 * 8;
  u16* lB0 = Blds + c0 * 8; u16* lB1 = Blds + c1 * 8;

  for (int kk = 0; kk < Kd; kk += 32) {
    gload_lds16(gA0 + kk, lA0);
    gload_lds16(gA1 + kk, lA1);
    gload_lds16(gB0 + kk, lB0);
    gload_lds16(gB1 + kk, lB1);
    __syncthreads();
    s16x8 af[4], bf[4];
#pragma unroll
    for (int m = 0; m < 4; ++m)
      af[m] = *(const s16x8*)(Alds + (wr + m * 16 + lr) * 32 + lg * 8);
#pragma unroll
    for (int nn = 0; nn < 4; ++nn)
      bf[nn] = *(const s16x8*)(Blds + (wc + nn * 16 + lr) * 32 + lg * 8);
#pragma unroll
    for (int m = 0; m < 4; ++m)
#pragma unroll
      for (int nn = 0; nn < 4; ++nn)
        acc[m][nn] = mfma_bf16(af[m], bf[nn], acc[m][nn]);
    __syncthreads();
  }

#pragma unroll
  for (int m = 0; m < 4; ++m)
#pragma unroll
    for (int nn = 0; nn < 4; ++nn)
#pragma unroll
      for (int r = 0; r < 4; ++r) {
        int row = trow + wr + m * 16 + lg * 4 + r;
        int col = tcol + wc + nn * 16 + lr;
        if constexpr (FBIAS)
          ((float*)Cv)[(size_t)row * Nd + col] = acc[m][nn][r] + bias[col];
        else
          ((u16*)Cv)[(size_t)row * Nd + col] = f2b(acc[m][nn][r]);
      }
}

// ---------------- RoPE in-place on bf16 Q,K (NSH layout) ----------------
__global__ void rope_inplace(u16* __restrict__ Qb, u16* __restrict__ Kb,
                             const int* __restrict__ pos) {
  int idx = blockIdx.x * blockDim.x + threadIdx.x;  // MROWS * 1024
  int row = idx >> 10;
  int pr = idx & 1023;
  int h = pr >> 6, j = pr & 63;
  int s = row & (SEQ - 1);
  float theta = expf(-0.14391156831f * (float)j);  // ln(10000)/64
  float ang = (float)pos[s] * theta;
  float sn, cs;
  sincosf(ang, &sn, &cs);
  size_t base = (size_t)row * HD + h * 128 + j;
  float q1 = b2f(Qb[base]), q2 = b2f(Qb[base + 64]);
  Qb[base] = f2b(q1 * cs - q2 * sn);
  Qb[base + 64] = f2b(q1 * sn + q2 * cs);
  float k1 = b2f(Kb[base]), k2 = b2f(Kb[base + 64]);
  Kb[base] = f2b(k1 * cs - k2 * sn);
  Kb[base + 64] = f2b(k1 * sn + k2 * cs);
}

// ---------------- Flash attention, causal, per (qtile=64, head, batch) -------
__global__ __launch_bounds__(256, 2) void attn_fwd(
    const u16* __restrict__ Qb, const u16* __restrict__ Kb,
    const u16* __restrict__ Vb, u16* __restrict__ Ctx) {
  __shared__ __align__(16) u16 Klds[32 * 128];
  __shared__ __align__(16) u16 Vt[128 * 32];     // V transposed: [d][kk]
  __shared__ __align__(16) u16 Plds[4][16 * 32]; // wave-private P tiles

  const int t = threadIdx.x;
  const int lane = t & 63, w = t >> 6;
  const int lr = lane & 15, lg = lane >> 4;
  const int qt = blockIdx.x, h = blockIdx.y, n = blockIdx.z;
  const int q0 = qt * 64 + w * 16;  // this wave's first q row
  const size_t hoff = (size_t)h * DHEAD;

  // Q fragments (A-operand): lane lr = q row, lg*8 = k chunk
  s16x8 qf[4];
#pragma unroll
  for (int c = 0; c < 4; ++c)
    qf[c] = *(const s16x8*)(Qb + (size_t)(n * SEQ + q0 + lr) * HD + hoff + c * 32 + lg * 8);

  f32x4 o[8] = {};
  float mrow[4] = {-1e30f, -1e30f, -1e30f, -1e30f};
  float lsum[4] = {0.f, 0.f, 0.f, 0.f};

  const int nkt = (qt + 1) * 2;           // k-tiles of 32 this block needs
  const int my_last = (q0 + 15) >> 5;     // last k-tile this wave computes

  for (int kt = 0; kt < nkt; ++kt) {
    // stage K tile (32x128) via global_load_lds; V tile transposed via scalar LDS
#pragma unroll
    for (int p = 0; p < 2; ++p) {
      int c = p * 256 + t;
      int r = c >> 4, ce = (c & 15) * 8;
      gload_lds16(Kb + (size_t)(n * SEQ + kt * 32 + r) * HD + hoff + ce, Klds + c * 8);
    }
#pragma unroll
    for (int p = 0; p < 2; ++p) {
      int c = p * 256 + t;
      int r = c >> 4, ce = (c & 15) * 8;
      s16x8 v = *(const s16x8*)(Vb + (size_t)(n * SEQ + kt * 32 + r) * HD + hoff + ce);
#pragma unroll
      for (int j = 0; j < 8; ++j) Vt[(ce + j) * 32 + r] = (u16)v[j];
    }
    __syncthreads();

    if (kt <= my_last) {
      // ---- QK^T: scores[16 q][32 k] ----
      f32x4 sc[2];
#pragma unroll
      for (int kb = 0; kb < 2; ++kb) {
        f32x4 a = {0.f, 0.f, 0.f, 0.f};
#pragma unroll
        for (int c = 0; c < 4; ++c) {
          s16x8 kf = *(const s16x8*)(Klds + (kb * 16 + lr) * 128 + c * 32 + lg * 8);
          a = mfma_bf16(qf[c], kf, a);
        }
        sc[kb] = a;
      }
      constexpr float scale = 0.08838834764831845f;  // 1/sqrt(128)
      float tmax[4];
#pragma unroll
      for (int r = 0; r < 4; ++r) {
        int qg = q0 + lg * 4 + r;
        float s0 = sc[0][r] * scale;
        float s1 = sc[1][r] * scale;
        if (kt * 32 + lr > qg) s0 = -1e30f;
        if (kt * 32 + 16 + lr > qg) s1 = -1e30f;
        sc[0][r] = s0; sc[1][r] = s1;
        tmax[r] = fmaxf(s0, s1);
      }
#pragma unroll
      for (int off = 1; off < 16; off <<= 1)
#pragma unroll
        for (int r = 0; r < 4; ++r)
          tmax[r] = fmaxf(tmax[r], __shfl_xor(tmax[r], off));

      float corr[4], rsum[4];
#pragma unroll
      for (int r = 0; r < 4; ++r) {
        float mnew = fmaxf(mrow[r], tmax[r]);
        corr[r] = __expf(mrow[r] - mnew);
        mrow[r] = mnew;
        float p0 = __expf(sc[0][r] - mnew);
        float p1 = __expf(sc[1][r] - mnew);
        rsum[r] = p0 + p1;
        Plds[w][(lg * 4 + r) * 32 + lr] = f2b(p0);
        Plds[w][(lg * 4 + r) * 32 + 16 + lr] = f2b(p1);
      }
#pragma unroll
      for (int off = 1; off < 16; off <<= 1)
#pragma unroll
        for (int r = 0; r < 4; ++r) rsum[r] += __shfl_xor(rsum[r], off);
#pragma unroll
      for (int r = 0; r < 4; ++r) lsum[r] = lsum[r] * corr[r] + rsum[r];
#pragma unroll
      for (int nb = 0; nb < 8; ++nb)
#pragma unroll
        for (int r = 0; r < 4; ++r) o[nb][r] *= corr[r];

      // ---- PV ----
      s16x8 pf = *(const s16x8*)(&Plds[w][lr * 32 + lg * 8]);
#pragma unroll
      for (int nb = 0; nb < 8; ++nb) {
        s16x8 vf = *(const s16x8*)(Vt + (nb * 16 + lr) * 32 + lg * 8);
        o[nb] = mfma_bf16(pf, vf, o[nb]);
      }
    }
    __syncthreads();
  }

  float inv[4];
#pragma unroll
  for (int r = 0; r < 4; ++r) inv[r] = 1.0f / lsum[r];
#pragma unroll
  for (int nb = 0; nb < 8; ++nb)
#pragma unroll
    for (int r = 0; r < 4; ++r)
      Ctx[(size_t)(n * SEQ + q0 + lg * 4 + r) * HD + hoff + nb * 16 + lr] =
          f2b(o[nb][r] * inv[r]);
}

// ---------------- host launch ----------------
extern "C" void kernel_launch(void* const* d_in, const int* in_sizes, int n_in,
                              void* d_out, int out_size, void* d_ws, size_t ws_size,
                              hipStream_t stream) {
  (void)in_sizes; (void)n_in; (void)out_size; (void)ws_size;
  const float* X  = (const float*)d_in[0];
  const int*  pos = (const int*)d_in[1];
  // d_in[2] (mask) is the causal tril; handled analytically.
  const float* Wq = (const float*)d_in[3];
  const float* Wk = (const float*)d_in[4];
  const float* Wv = (const float*)d_in[5];
  const float* Wo = (const float*)d_in[6];
  const float* bo = (const float*)d_in[7];
  float* out = (float*)d_out;

  constexpr size_t XE = (size_t)MROWS * HD;  // 8.4M elems
  constexpr size_t WE = (size_t)HD * HD;     // 4.2M elems

  char* p = (char*)d_ws;
  u16* Xb  = (u16*)p; p += XE * 2;
  u16* Wqb = (u16*)p; p += WE * 2;
  u16* Wkb = (u16*)p; p += WE * 2;
  u16* Wvb = (u16*)p; p += WE * 2;
  u16* Wob = (u16*)p; p += WE * 2;
  u16* Qb  = (u16*)p; p += XE * 2;
  u16* Kb  = (u16*)p; p += XE * 2;
  u16* Vb  = (u16*)p; p += XE * 2;
  u16* Ctx = Xb;  // X no longer needed once Q,K,V exist

  cvt_bf16<<<(int)(XE / 8 / 256), 256, 0, stream>>>(X, Xb, (int)(XE / 8));
  cvt_bf16<<<(int)(WE / 8 / 256), 256, 0, stream>>>(Wq, Wqb, (int)(WE / 8));
  cvt_bf16<<<(int)(WE / 8 / 256), 256, 0, stream>>>(Wk, Wkb, (int)(WE / 8));
  cvt_bf16<<<(int)(WE / 8 / 256), 256, 0, stream>>>(Wv, Wvb, (int)(WE / 8));
  cvt_bf16<<<(int)(WE / 8 / 256), 256, 0, stream>>>(Wo, Wob, (int)(WE / 8));

  dim3 g(HD / 128, MROWS / 128);  // (16, 32)
  gemm_nt<false><<<g, 256, 0, stream>>>(Xb, Wqb, Qb, nullptr, HD, HD);
  gemm_nt<false><<<g, 256, 0, stream>>>(Xb, Wkb, Kb, nullptr, HD, HD);
  gemm_nt<false><<<g, 256, 0, stream>>>(Xb, Wvb, Vb, nullptr, HD, HD);

  rope_inplace<<<MROWS * 1024 / 256, 256, 0, stream>>>(Qb, Kb, pos);

  attn_fwd<<<dim3(SEQ / 64, NHEADS, NB), 256, 0, stream>>>(Qb, Kb, Vb, Ctx);

  gemm_nt<true><<<g, 256, 0, stream>>>(Ctx, Wob, out, bo, HD, HD);
}

// Round 2
// 547.733 us; speedup vs baseline: 1.5440x; 1.5440x over previous
//
#include <hip/hip_runtime.h>
#include <hip/hip_bf16.h>
#include <stdint.h>

typedef unsigned short u16;
typedef __attribute__((ext_vector_type(4))) float f32x4;
typedef __attribute__((ext_vector_type(8))) short s16x8;
typedef __attribute__((ext_vector_type(8))) __bf16 b16x8;

constexpr int NB = 2, SEQ = 2048, HD = 2048, NHEADS = 16, DHEAD = 128;
constexpr int MROWS = NB * SEQ;  // 4096

__device__ __forceinline__ u16 f2b(float f) {
  __hip_bfloat16 h = __float2bfloat16(f);
  return __builtin_bit_cast(u16, h);
}
__device__ __forceinline__ float b2f(u16 u) {
  return __bfloat162float(__builtin_bit_cast(__hip_bfloat16, u));
}
__device__ __forceinline__ f32x4 mfma_bf16(s16x8 a, s16x8 b, f32x4 c) {
  return __builtin_amdgcn_mfma_f32_16x16x32_bf16(
      __builtin_bit_cast(b16x8, a), __builtin_bit_cast(b16x8, b), c, 0, 0, 0);
}
__device__ __forceinline__ void gload_lds16(const void* g, void* l) {
  __builtin_amdgcn_global_load_lds(
      (__attribute__((address_space(1))) void*)(const_cast<void*>(g)),
      (__attribute__((address_space(3))) void*)(l), 16, 0, 0);
}

// ---------------- f32 -> bf16 convert (8 elems / thread) ----------------
__global__ void cvt_bf16(const float* __restrict__ in, u16* __restrict__ out, int n8) {
  int i = blockIdx.x * blockDim.x + threadIdx.x;
  if (i >= n8) return;
  const float4* p = (const float4*)(in + (size_t)i * 8);
  float4 a = p[0], b = p[1];
  ushort4* q = (ushort4*)(out + (size_t)i * 8);
  q[0] = make_ushort4(f2b(a.x), f2b(a.y), f2b(a.z), f2b(a.w));
  q[1] = make_ushort4(f2b(b.x), f2b(b.y), f2b(b.z), f2b(b.w));
}

// ---------------- NT GEMM: C[M,N] = A[M,K] * B[N,K]^T (+bias) ----------------
template <bool FBIAS>
__global__ __launch_bounds__(256, 2) void gemm_nt(
    const u16* __restrict__ A, const u16* __restrict__ B, void* __restrict__ Cv,
    const float* __restrict__ bias, int Kd, int Nd) {
  __shared__ __align__(16) u16 Alds[128 * 32];
  __shared__ __align__(16) u16 Blds[128 * 32];
  const int t = threadIdx.x;
  const int lane = t & 63, w = t >> 6;
  const int lr = lane & 15, lg = lane >> 4;
  const int wr = (w >> 1) * 64, wc = (w & 1) * 64;
  const int trow = blockIdx.y * 128, tcol = blockIdx.x * 128;

  f32x4 acc[4][4] = {};

  const int c0 = t, c1 = t + 256;
  const u16* gA0 = A + (size_t)(trow + (c0 >> 2)) * Kd + (c0 & 3) * 8;
  const u16* gA1 = A + (size_t)(trow + (c1 >> 2)) * Kd + (c1 & 3) * 8;
  const u16* gB0 = B + (size_t)(tcol + (c0 >> 2)) * Kd + (c0 & 3) * 8;
  const u16* gB1 = B + (size_t)(tcol + (c1 >> 2)) * Kd + (c1 & 3) * 8;
  u16* lA0 = Alds + c0 * 8; u16* lA1 = Alds + c1 * 8;
  u16* lB0 = Blds + c0 * 8; u16* lB1 = Blds + c1 * 8;

  for (int kk = 0; kk < Kd; kk += 32) {
    gload_lds16(gA0 + kk, lA0);
    gload_lds16(gA1 + kk, lA1);
    gload_lds16(gB0 + kk, lB0);
    gload_lds16(gB1 + kk, lB1);
    __syncthreads();
    s16x8 af[4], bf[4];
#pragma unroll
    for (int m = 0; m < 4; ++m)
      af[m] = *(const s16x8*)(Alds + (wr + m * 16 + lr) * 32 + lg * 8);
#pragma unroll
    for (int nn = 0; nn < 4; ++nn)
      bf[nn] = *(const s16x8*)(Blds + (wc + nn * 16 + lr) * 32 + lg * 8);
#pragma unroll
    for (int m = 0; m < 4; ++m)
#pragma unroll
      for (int nn = 0; nn < 4; ++nn)
        acc[m][nn] = mfma_bf16(af[m], bf[nn], acc[m][nn]);
    __syncthreads();
  }

#pragma unroll
  for (int m = 0; m < 4; ++m)
#pragma unroll
    for (int nn = 0; nn < 4; ++nn)
#pragma unroll
      for (int r = 0; r < 4; ++r) {
        int row = trow + wr + m * 16 + lg * 4 + r;
        int col = tcol + wc + nn * 16 + lr;
        if constexpr (FBIAS)
          ((float*)Cv)[(size_t)row * Nd + col] = acc[m][nn][r] + bias[col];
        else
          ((u16*)Cv)[(size_t)row * Nd + col] = f2b(acc[m][nn][r]);
      }
}

// ---------------- RoPE in-place on bf16 Q,K (NSH layout) ----------------
__global__ void rope_inplace(u16* __restrict__ Qb, u16* __restrict__ Kb,
                             const int* __restrict__ pos) {
  int idx = blockIdx.x * blockDim.x + threadIdx.x;
  int row = idx >> 10;
  int pr = idx & 1023;
  int h = pr >> 6, j = pr & 63;
  int s = row & (SEQ - 1);
  float theta = expf(-0.14391156831f * (float)j);  // ln(10000)/64
  float ang = (float)pos[s] * theta;
  float sn, cs;
  sincosf(ang, &sn, &cs);
  size_t base = (size_t)row * HD + h * 128 + j;
  float q1 = b2f(Qb[base]), q2 = b2f(Qb[base + 64]);
  Qb[base] = f2b(q1 * cs - q2 * sn);
  Qb[base + 64] = f2b(q1 * sn + q2 * cs);
  float k1 = b2f(Kb[base]), k2 = b2f(Kb[base + 64]);
  Kb[base] = f2b(k1 * cs - k2 * sn);
  Kb[base + 64] = f2b(k1 * sn + k2 * cs);
}

// ---------------- Flash attention v2: KVBLK=64, swizzled LDS ----------------
// Vt is V pre-transposed: [h*128+d][n*SEQ+s]
__global__ __launch_bounds__(256, 4) void attn_fwd(
    const u16* __restrict__ Qb, const u16* __restrict__ Kb,
    const u16* __restrict__ Vt, u16* __restrict__ Ctx) {
  __shared__ __align__(16) u16 Klds[64 * 128];   // [krow][d], chunk^(row&7)
  __shared__ __align__(16) u16 Vlds[128 * 64];   // [d][krow], chunk^(row&7)
  __shared__ __align__(16) u16 Plds[4][16 * 64]; // per-wave, chunk^(row&7)

  const int t = threadIdx.x;
  const int lane = t & 63, w = t >> 6;
  const int lr = lane & 15, lg = lane >> 4;
  const int qt = (int)gridDim.x - 1 - (int)blockIdx.x;  // heavy blocks first
  const int h = blockIdx.y, n = blockIdx.z;
  const int q0 = qt * 64 + w * 16;
  const size_t hoff = (size_t)h * DHEAD;

  // Q fragments: lane lr = q row, lg*8 = d chunk within 32-slice c
  s16x8 qf[4];
#pragma unroll
  for (int c = 0; c < 4; ++c)
    qf[c] = *(const s16x8*)(Qb + (size_t)(n * SEQ + q0 + lr) * HD + hoff + c * 32 + lg * 8);

  f32x4 o[8] = {};
  float mrow[4] = {-1e30f, -1e30f, -1e30f, -1e30f};
  float lsum[4] = {0.f, 0.f, 0.f, 0.f};

  const int nkt = qt + 1;  // k-tiles of 64

  for (int kt = 0; kt < nkt; ++kt) {
    // ---- stage K tile [64][128]: 1024 chunks, source pre-swizzled ----
#pragma unroll
    for (int p = 0; p < 4; ++p) {
      int q = p * 256 + t;
      int r = q >> 4, cs = (q & 15) ^ (r & 7);
      gload_lds16(Kb + (size_t)(n * SEQ + kt * 64 + r) * HD + hoff + cs * 8,
                  Klds + q * 8);
    }
    // ---- stage Vt tile [128][64]: 1024 chunks, source pre-swizzled ----
#pragma unroll
    for (int p = 0; p < 4; ++p) {
      int q = p * 256 + t;
      int r = q >> 3, cs = (q & 7) ^ (r & 7);
      gload_lds16(Vt + (size_t)(hoff + r) * MROWS + n * SEQ + kt * 64 + cs * 8,
                  Vlds + q * 8);
    }
    __syncthreads();

    // ---- QK^T: scores[16 q][64 k] ----
    f32x4 sc[4];
#pragma unroll
    for (int kb = 0; kb < 4; ++kb) {
      f32x4 a = {0.f, 0.f, 0.f, 0.f};
#pragma unroll
      for (int c = 0; c < 4; ++c) {
        s16x8 kf = *(const s16x8*)(Klds + (kb * 16 + lr) * 128 +
                                   (((c * 4 + lg) ^ (lr & 7))) * 8);
        a = mfma_bf16(qf[c], kf, a);
      }
      sc[kb] = a;
    }

    constexpr float scale = 0.08838834764831845f;  // 1/sqrt(128)
    float tmax[4] = {-1e30f, -1e30f, -1e30f, -1e30f};
#pragma unroll
    for (int r = 0; r < 4; ++r) {
      int qg = q0 + lg * 4 + r;
#pragma unroll
      for (int kb = 0; kb < 4; ++kb) {
        float s = sc[kb][r] * scale;
        if (kt * 64 + kb * 16 + lr > qg) s = -1e30f;
        sc[kb][r] = s;
        tmax[r] = fmaxf(tmax[r], s);
      }
    }
#pragma unroll
    for (int off = 1; off < 16; off <<= 1)
#pragma unroll
      for (int r = 0; r < 4; ++r)
        tmax[r] = fmaxf(tmax[r], __shfl_xor(tmax[r], off));

    float corr[4], rsum[4];
#pragma unroll
    for (int r = 0; r < 4; ++r) {
      float mnew = fmaxf(mrow[r], tmax[r]);
      corr[r] = __expf(mrow[r] - mnew);
      mrow[r] = mnew;
      rsum[r] = 0.f;
      int prow = lg * 4 + r;
#pragma unroll
      for (int kb = 0; kb < 4; ++kb) {
        float pv = __expf(sc[kb][r] - mnew);
        rsum[r] += pv;
        int col = kb * 16 + lr;
        Plds[w][prow * 64 + ((col >> 3) ^ (prow & 7)) * 8 + (col & 7)] = f2b(pv);
      }
    }
#pragma unroll
    for (int off = 1; off < 16; off <<= 1)
#pragma unroll
      for (int r = 0; r < 4; ++r) rsum[r] += __shfl_xor(rsum[r], off);
#pragma unroll
    for (int r = 0; r < 4; ++r) lsum[r] = lsum[r] * corr[r] + rsum[r];
#pragma unroll
    for (int nb = 0; nb < 8; ++nb)
#pragma unroll
      for (int r = 0; r < 4; ++r) o[nb][r] *= corr[r];

    // ---- PV: O[16 q][128 d] += P[16][64] * V[64][128] ----
    s16x8 pf0 = *(const s16x8*)(&Plds[w][lr * 64 + ((lg) ^ (lr & 7)) * 8]);
    s16x8 pf1 = *(const s16x8*)(&Plds[w][lr * 64 + ((4 + lg) ^ (lr & 7)) * 8]);
#pragma unroll
    for (int nb = 0; nb < 8; ++nb) {
      int vrow = nb * 16 + lr;
      s16x8 vf0 = *(const s16x8*)(Vlds + vrow * 64 + ((lg) ^ (lr & 7)) * 8);
      s16x8 vf1 = *(const s16x8*)(Vlds + vrow * 64 + ((4 + lg) ^ (lr & 7)) * 8);
      o[nb] = mfma_bf16(pf0, vf0, o[nb]);
      o[nb] = mfma_bf16(pf1, vf1, o[nb]);
    }
    __syncthreads();
  }

  float inv[4];
#pragma unroll
  for (int r = 0; r < 4; ++r) inv[r] = 1.0f / lsum[r];
#pragma unroll
  for (int nb = 0; nb < 8; ++nb)
#pragma unroll
    for (int r = 0; r < 4; ++r)
      Ctx[(size_t)(n * SEQ + q0 + lg * 4 + r) * HD + hoff + nb * 16 + lr] =
          f2b(o[nb][r] * inv[r]);
}

// ---------------- host launch ----------------
extern "C" void kernel_launch(void* const* d_in, const int* in_sizes, int n_in,
                              void* d_out, int out_size, void* d_ws, size_t ws_size,
                              hipStream_t stream) {
  (void)in_sizes; (void)n_in; (void)out_size; (void)ws_size;
  const float* X  = (const float*)d_in[0];
  const int*  pos = (const int*)d_in[1];
  const float* Wq = (const float*)d_in[3];
  const float* Wk = (const float*)d_in[4];
  const float* Wv = (const float*)d_in[5];
  const float* Wo = (const float*)d_in[6];
  const float* bo = (const float*)d_in[7];
  float* out = (float*)d_out;

  constexpr size_t XE = (size_t)MROWS * HD;
  constexpr size_t WE = (size_t)HD * HD;

  char* p = (char*)d_ws;
  u16* Xb  = (u16*)p; p += XE * 2;
  u16* Wqb = (u16*)p; p += WE * 2;
  u16* Wkb = (u16*)p; p += WE * 2;
  u16* Wvb = (u16*)p; p += WE * 2;
  u16* Wob = (u16*)p; p += WE * 2;
  u16* Qb  = (u16*)p; p += XE * 2;
  u16* Kb  = (u16*)p; p += XE * 2;
  u16* Vtb = (u16*)p; p += XE * 2;  // V^T: [h*128+d][n*SEQ+s]
  u16* Ctx = Xb;  // X no longer needed once Q,K,V exist

  cvt_bf16<<<(int)(XE / 8 / 256), 256, 0, stream>>>(X, Xb, (int)(XE / 8));
  cvt_bf16<<<(int)(WE / 8 / 256), 256, 0, stream>>>(Wq, Wqb, (int)(WE / 8));
  cvt_bf16<<<(int)(WE / 8 / 256), 256, 0, stream>>>(Wk, Wkb, (int)(WE / 8));
  cvt_bf16<<<(int)(WE / 8 / 256), 256, 0, stream>>>(Wv, Wvb, (int)(WE / 8));
  cvt_bf16<<<(int)(WE / 8 / 256), 256, 0, stream>>>(Wo, Wob, (int)(WE / 8));

  dim3 g(HD / 128, MROWS / 128);   // (16, 32)
  gemm_nt<false><<<g, 256, 0, stream>>>(Xb, Wqb, Qb, nullptr, HD, HD);
  gemm_nt<false><<<g, 256, 0, stream>>>(Xb, Wkb, Kb, nullptr, HD, HD);
  // V^T = Wv * X^T  -> [2048][4096], no separate transpose needed
  dim3 gv(MROWS / 128, HD / 128);  // (32, 16)
  gemm_nt<false><<<gv, 256, 0, stream>>>(Wvb, Xb, Vtb, nullptr, HD, MROWS);

  rope_inplace<<<MROWS * 1024 / 256, 256, 0, stream>>>(Qb, Kb, pos);

  attn_fwd<<<dim3(SEQ / 64, NHEADS, NB), 256, 0, stream>>>(Qb, Kb, Vtb, Ctx);

  gemm_nt<true><<<g, 256, 0, stream>>>(Ctx, Wob, out, bo, HD, HD);
}

// Round 3
// 462.087 us; speedup vs baseline: 1.8301x; 1.1853x over previous
//
#include <hip/hip_runtime.h>
#include <hip/hip_bf16.h>
#include <stdint.h>

typedef unsigned short u16;
typedef __attribute__((ext_vector_type(4))) float f32x4;
typedef __attribute__((ext_vector_type(8))) short s16x8;
typedef __attribute__((ext_vector_type(8))) __bf16 b16x8;

constexpr int NB = 2, SEQ = 2048, HD = 2048, NHEADS = 16, DHEAD = 128;
constexpr int MROWS = NB * SEQ;  // 4096

__device__ __forceinline__ u16 f2b(float f) {
  __hip_bfloat16 h = __float2bfloat16(f);
  return __builtin_bit_cast(u16, h);
}
__device__ __forceinline__ float b2f(u16 u) {
  return __bfloat162float(__builtin_bit_cast(__hip_bfloat16, u));
}
__device__ __forceinline__ f32x4 mfma_bf16(s16x8 a, s16x8 b, f32x4 c) {
  return __builtin_amdgcn_mfma_f32_16x16x32_bf16(
      __builtin_bit_cast(b16x8, a), __builtin_bit_cast(b16x8, b), c, 0, 0, 0);
}
__device__ __forceinline__ void gload_lds16(const void* g, void* l) {
  __builtin_amdgcn_global_load_lds(
      (__attribute__((address_space(1))) void*)(const_cast<void*>(g)),
      (__attribute__((address_space(3))) void*)(l), 16, 0, 0);
}

// ---------------- f32 -> bf16 convert (8 elems / thread) ----------------
__global__ void cvt_bf16(const float* __restrict__ in, u16* __restrict__ out, int n8) {
  int i = blockIdx.x * blockDim.x + threadIdx.x;
  if (i >= n8) return;
  const float4* p = (const float4*)(in + (size_t)i * 8);
  float4 a = p[0], b = p[1];
  ushort4* q = (ushort4*)(out + (size_t)i * 8);
  q[0] = make_ushort4(f2b(a.x), f2b(a.y), f2b(a.z), f2b(a.w));
  q[1] = make_ushort4(f2b(b.x), f2b(b.y), f2b(b.z), f2b(b.w));
}

// ---------------- NT GEMM: C[M,N] = A[M,K] * B[N,K]^T (+bias) ----------------
template <bool FBIAS>
__global__ __launch_bounds__(256, 2) void gemm_nt(
    const u16* __restrict__ A, const u16* __restrict__ B, void* __restrict__ Cv,
    const float* __restrict__ bias, int Kd, int Nd) {
  __shared__ __align__(16) u16 Alds[128 * 32];
  __shared__ __align__(16) u16 Blds[128 * 32];
  const int t = threadIdx.x;
  const int lane = t & 63, w = t >> 6;
  const int lr = lane & 15, lg = lane >> 4;
  const int wr = (w >> 1) * 64, wc = (w & 1) * 64;
  const int trow = blockIdx.y * 128, tcol = blockIdx.x * 128;

  f32x4 acc[4][4] = {};

  const int c0 = t, c1 = t + 256;
  const u16* gA0 = A + (size_t)(trow + (c0 >> 2)) * Kd + (c0 & 3) * 8;
  const u16* gA1 = A + (size_t)(trow + (c1 >> 2)) * Kd + (c1 & 3) * 8;
  const u16* gB0 = B + (size_t)(tcol + (c0 >> 2)) * Kd + (c0 & 3) * 8;
  const u16* gB1 = B + (size_t)(tcol + (c1 >> 2)) * Kd + (c1 & 3) * 8;
  u16* lA0 = Alds + c0 * 8; u16* lA1 = Alds + c1 * 8;
  u16* lB0 = Blds + c0 * 8; u16* lB1 = Blds + c1 * 8;

  for (int kk = 0; kk < Kd; kk += 32) {
    gload_lds16(gA0 + kk, lA0);
    gload_lds16(gA1 + kk, lA1);
    gload_lds16(gB0 + kk, lB0);
    gload_lds16(gB1 + kk, lB1);
    __syncthreads();
    s16x8 af[4], bf[4];
#pragma unroll
    for (int m = 0; m < 4; ++m)
      af[m] = *(const s16x8*)(Alds + (wr + m * 16 + lr) * 32 + lg * 8);
#pragma unroll
    for (int nn = 0; nn < 4; ++nn)
      bf[nn] = *(const s16x8*)(Blds + (wc + nn * 16 + lr) * 32 + lg * 8);
#pragma unroll
    for (int m = 0; m < 4; ++m)
#pragma unroll
      for (int nn = 0; nn < 4; ++nn)
        acc[m][nn] = mfma_bf16(af[m], bf[nn], acc[m][nn]);
    __syncthreads();
  }

#pragma unroll
  for (int m = 0; m < 4; ++m)
#pragma unroll
    for (int nn = 0; nn < 4; ++nn)
#pragma unroll
      for (int r = 0; r < 4; ++r) {
        int row = trow + wr + m * 16 + lg * 4 + r;
        int col = tcol + wc + nn * 16 + lr;
        if constexpr (FBIAS)
          ((float*)Cv)[(size_t)row * Nd + col] = acc[m][nn][r] + bias[col];
        else
          ((u16*)Cv)[(size_t)row * Nd + col] = f2b(acc[m][nn][r]);
      }
}

// ---------------- RoPE in-place; Q pre-scaled by (1/sqrt(dh))*log2(e) --------
__global__ void rope_inplace(u16* __restrict__ Qb, u16* __restrict__ Kb,
                             const int* __restrict__ pos) {
  const float QSC = 0.08838834764831845f * 1.4426950408889634f;
  int idx = blockIdx.x * blockDim.x + threadIdx.x;
  int row = idx >> 10;
  int pr = idx & 1023;
  int h = pr >> 6, j = pr & 63;
  int s = row & (SEQ - 1);
  float theta = expf(-0.14391156831f * (float)j);  // ln(10000)/64
  float ang = (float)pos[s] * theta;
  float sn, cs;
  sincosf(ang, &sn, &cs);
  size_t base = (size_t)row * HD + h * 128 + j;
  float q1 = b2f(Qb[base]), q2 = b2f(Qb[base + 64]);
  Qb[base] = f2b((q1 * cs - q2 * sn) * QSC);
  Qb[base + 64] = f2b((q1 * sn + q2 * cs) * QSC);
  float k1 = b2f(Kb[base]), k2 = b2f(Kb[base + 64]);
  Kb[base] = f2b(k1 * cs - k2 * sn);
  Kb[base + 64] = f2b(k1 * sn + k2 * cs);
}

// ---------------- Flash attention v3 ----------------
// QBLK=128 (8 waves x 16 q), KVBLK=64, double-buffered K/V, swapped QK^T.
// Vt is V pre-transposed: [h*128+d][n*SEQ+s].
__global__ __launch_bounds__(512, 4) void attn_fwd(
    const u16* __restrict__ Qb, const u16* __restrict__ Kb,
    const u16* __restrict__ Vt, u16* __restrict__ Ctx) {
  constexpr int KSZ = 64 * 128;
  __shared__ __align__(16) u16 Klds[2 * KSZ];   // [buf][krow][d], chunk^(krow&7)
  __shared__ __align__(16) u16 Vlds[2 * KSZ];   // [buf][d][krow], chunk^(d&7)
  __shared__ __align__(16) u16 Plds[8 * 1024];  // per-wave [16 q][64 k], kk^((q&7)<<3)

  const int t = threadIdx.x;
  const int lane = t & 63, w = t >> 6;
  const int lr = lane & 15, lg = lane >> 4;

  // XCD swizzle: blocks sharing (h,n) KV panel land on one XCD; heavy qt first
  const int f = blockIdx.x;
  const int xcd = f & 7, j = f >> 3;
  const int pp = xcd + 8 * (j >> 4);
  const int qt = 15 - (j & 15);
  const int h = pp & 15, n = pp >> 4;

  const int q0 = qt * 128 + w * 16;  // wave's first q row
  const int qg = q0 + lr;            // this lane's q row
  const size_t hoff = (size_t)h * DHEAD;

  // ---- staging addresses: 2 K chunks + 2 V chunks per thread ----
  const int kq0 = t, kq1 = t + 512;
  const int kr0 = kq0 >> 4, kr1 = kq1 >> 4;
  const u16* gK0 = Kb + (size_t)(n * SEQ + kr0) * HD + hoff + ((kq0 & 15) ^ (kr0 & 7)) * 8;
  const u16* gK1 = Kb + (size_t)(n * SEQ + kr1) * HD + hoff + ((kq1 & 15) ^ (kr1 & 7)) * 8;
  u16* lK0 = Klds + kq0 * 8;
  u16* lK1 = Klds + kq1 * 8;
  const int vr0 = kq0 >> 3, vr1 = kq1 >> 3;
  const u16* gV0 = Vt + (size_t)(hoff + vr0) * MROWS + n * SEQ + ((kq0 & 7) ^ (vr0 & 7)) * 8;
  const u16* gV1 = Vt + (size_t)(hoff + vr1) * MROWS + n * SEQ + ((kq1 & 7) ^ (vr1 & 7)) * 8;
  u16* lV0 = Vlds + kq0 * 8;
  u16* lV1 = Vlds + kq1 * 8;

  // ---- Q fragments (B-operand: col=q=lr, k=d) ----
  s16x8 qf[4];
#pragma unroll
  for (int c = 0; c < 4; ++c)
    qf[c] = *(const s16x8*)(Qb + (size_t)(n * SEQ + qg) * HD + hoff + c * 32 + lg * 8);

  f32x4 o[8] = {};                  // O^T: d = nb*16+lg*4+r, q = q0+lr
  float mrow = -3.0e38f, lsum = 0.f;
  u16* PW = Plds + w * 1024;

  const int nkt = 2 * qt + 2;

  // prologue: stage tile 0 into buf 0
  gload_lds16(gK0, lK0);
  gload_lds16(gK1, lK1);
  gload_lds16(gV0, lV0);
  gload_lds16(gV1, lV1);
  __syncthreads();

  for (int kt = 0; kt < nkt; ++kt) {
    const int cur = kt & 1;
    const u16* Kc = Klds + cur * KSZ;
    const u16* Vc = Vlds + cur * KSZ;
    const int ktb = kt * 64;

    if (kt + 1 < nkt) {  // issue next-tile stage into other buffer
      const int b1 = (cur ^ 1) * KSZ;
      const size_t ko = (size_t)(kt + 1) * 64 * HD;
      const int vo = (kt + 1) * 64;
      gload_lds16(gK0 + ko, lK0 + b1);
      gload_lds16(gK1 + ko, lK1 + b1);
      gload_lds16(gV0 + vo, lV0 + b1);
      gload_lds16(gV1 + vo, lV1 + b1);
    }

    if (ktb <= q0 + 15) {  // wave-uniform: skip fully-masked waves
      // ---- S^T = K·Q : sc[kb][r] = S[q0+lr][ktb + kb*16 + lg*4 + r] ----
      f32x4 sc[4];
#pragma unroll
      for (int kb = 0; kb < 4; ++kb) {
        f32x4 a = {0.f, 0.f, 0.f, 0.f};
        const u16* krow = Kc + (kb * 16 + lr) * 128;
#pragma unroll
        for (int c = 0; c < 4; ++c) {
          s16x8 kf = *(const s16x8*)(krow + ((c * 4 + lg) ^ (lr & 7)) * 8);
          a = mfma_bf16(kf, qf[c], a);
        }
        sc[kb] = a;
      }

      if (ktb + 63 > q0) {  // diagonal region: causal mask (scores pre-scaled)
#pragma unroll
        for (int kb = 0; kb < 4; ++kb)
#pragma unroll
          for (int r = 0; r < 4; ++r)
            if (ktb + kb * 16 + lg * 4 + r > qg) sc[kb][r] = -3.0e38f;
      }

      // ---- online softmax (log2 domain), defer-max THR=8 ----
      float tm = -3.0e38f;
#pragma unroll
      for (int kb = 0; kb < 4; ++kb)
#pragma unroll
        for (int r = 0; r < 4; ++r) tm = fmaxf(tm, sc[kb][r]);
      tm = fmaxf(tm, __shfl_xor(tm, 16));
      tm = fmaxf(tm, __shfl_xor(tm, 32));
      if (!__all(tm - mrow <= 8.0f)) {
        float mn = fmaxf(mrow, tm);
        float corr = exp2f(mrow - mn);
        mrow = mn;
        lsum *= corr;
#pragma unroll
        for (int nb = 0; nb < 8; ++nb)
#pragma unroll
          for (int r = 0; r < 4; ++r) o[nb][r] *= corr;
      }

      float rs = 0.f;
#pragma unroll
      for (int kb = 0; kb < 4; ++kb) {
        float p0 = exp2f(sc[kb][0] - mrow);
        float p1 = exp2f(sc[kb][1] - mrow);
        float p2 = exp2f(sc[kb][2] - mrow);
        float p3 = exp2f(sc[kb][3] - mrow);
        rs += (p0 + p1) + (p2 + p3);
        *(ushort4*)(PW + lr * 64 + ((kb * 16 + lg * 4) ^ ((lr & 7) * 8))) =
            make_ushort4(f2b(p0), f2b(p1), f2b(p2), f2b(p3));
      }
      rs += __shfl_xor(rs, 16);
      rs += __shfl_xor(rs, 32);
      lsum += rs;

      // ---- O^T += V^T · P^T ----
      s16x8 pf0 = *(const s16x8*)(PW + lr * 64 + ((lg ^ (lr & 7))) * 8);
      s16x8 pf1 = *(const s16x8*)(PW + lr * 64 + (((4 + lg) ^ (lr & 7))) * 8);
#pragma unroll
      for (int nb = 0; nb < 8; ++nb) {
        const u16* vrow = Vc + (nb * 16 + lr) * 64;
        s16x8 vf0 = *(const s16x8*)(vrow + ((lg ^ (lr & 7))) * 8);
        s16x8 vf1 = *(const s16x8*)(vrow + (((4 + lg) ^ (lr & 7))) * 8);
        o[nb] = mfma_bf16(vf0, pf0, o[nb]);
        o[nb] = mfma_bf16(vf1, pf1, o[nb]);
      }
    }
    __syncthreads();
  }

  const float inv = 1.0f / lsum;
  u16* crow = Ctx + (size_t)(n * SEQ + qg) * HD + hoff;
#pragma unroll
  for (int nb = 0; nb < 8; ++nb)
    *(ushort4*)(crow + nb * 16 + lg * 4) =
        make_ushort4(f2b(o[nb][0] * inv), f2b(o[nb][1] * inv),
                     f2b(o[nb][2] * inv), f2b(o[nb][3] * inv));
}

// ---------------- host launch ----------------
extern "C" void kernel_launch(void* const* d_in, const int* in_sizes, int n_in,
                              void* d_out, int out_size, void* d_ws, size_t ws_size,
                              hipStream_t stream) {
  (void)in_sizes; (void)n_in; (void)out_size; (void)ws_size;
  const float* X  = (const float*)d_in[0];
  const int*  pos = (const int*)d_in[1];
  const float* Wq = (const float*)d_in[3];
  const float* Wk = (const float*)d_in[4];
  const float* Wv = (const float*)d_in[5];
  const float* Wo = (const float*)d_in[6];
  const float* bo = (const float*)d_in[7];
  float* out = (float*)d_out;

  constexpr size_t XE = (size_t)MROWS * HD;
  constexpr size_t WE = (size_t)HD * HD;

  char* p = (char*)d_ws;
  u16* Xb  = (u16*)p; p += XE * 2;
  u16* Wqb = (u16*)p; p += WE * 2;
  u16* Wkb = (u16*)p; p += WE * 2;
  u16* Wvb = (u16*)p; p += WE * 2;
  u16* Wob = (u16*)p; p += WE * 2;
  u16* Qb  = (u16*)p; p += XE * 2;
  u16* Kb  = (u16*)p; p += XE * 2;
  u16* Vtb = (u16*)p; p += XE * 2;  // V^T: [h*128+d][n*SEQ+s]
  u16* Ctx = Xb;  // X no longer needed once Q,K,V exist

  cvt_bf16<<<(int)(XE / 8 / 256), 256, 0, stream>>>(X, Xb, (int)(XE / 8));
  cvt_bf16<<<(int)(WE / 8 / 256), 256, 0, stream>>>(Wq, Wqb, (int)(WE / 8));
  cvt_bf16<<<(int)(WE / 8 / 256), 256, 0, stream>>>(Wk, Wkb, (int)(WE / 8));
  cvt_bf16<<<(int)(WE / 8 / 256), 256, 0, stream>>>(Wv, Wvb, (int)(WE / 8));
  cvt_bf16<<<(int)(WE / 8 / 256), 256, 0, stream>>>(Wo, Wob, (int)(WE / 8));

  dim3 g(HD / 128, MROWS / 128);   // (16, 32)
  gemm_nt<false><<<g, 256, 0, stream>>>(Xb, Wqb, Qb, nullptr, HD, HD);
  gemm_nt<false><<<g, 256, 0, stream>>>(Xb, Wkb, Kb, nullptr, HD, HD);
  // V^T = Wv * X^T  -> [2048][4096]
  dim3 gv(MROWS / 128, HD / 128);  // (32, 16)
  gemm_nt<false><<<gv, 256, 0, stream>>>(Wvb, Xb, Vtb, nullptr, HD, MROWS);

  rope_inplace<<<MROWS * 1024 / 256, 256, 0, stream>>>(Qb, Kb, pos);

  attn_fwd<<<dim3(512), 512, 0, stream>>>(Qb, Kb, Vtb, Ctx);

  gemm_nt<true><<<g, 256, 0, stream>>>(Ctx, Wob, out, bo, HD, HD);
}